// Round 2
// baseline (137.893 us; speedup 1.0000x reference)
//
#include <hip/hip_runtime.h>
#include <math.h>

#define NPTS   8192
#define CHUNK  1024
#define BLOCK  256
#define NCHUNK (NPTS / CHUNK)   // 8

// ---------------------------------------------------------------------------
// Kernel 1: partial NN min. grid = (NPTS/BLOCK, NCHUNK, 2).
// z=0: queries=predict, db=gt (fwd); z=1: queries=gt, db=predict (bwd).
// Each block stages CHUNK db points into LDS as float4 (x,y,z,|g|^2) and
// computes, for its 256 queries, min_j (|g|^2 - 2 p.g); adds |p|^2 at end.
// Writes partial[(z*NCHUNK + cy)*NPTS + i] — no atomics, no init needed.
// ---------------------------------------------------------------------------
__global__ void __launch_bounds__(BLOCK)
nn_partial_kernel(const float* __restrict__ P, const float* __restrict__ G,
                  float* __restrict__ partial) {
    const float* __restrict__ A = blockIdx.z ? G : P;  // queries
    const float* __restrict__ B = blockIdx.z ? P : G;  // database

    __shared__ float4 sB[CHUNK];
    const int jbase = blockIdx.y * CHUNK;
    for (int t = threadIdx.x; t < CHUNK; t += BLOCK) {
        const float x = B[jbase + t];
        const float y = B[NPTS + jbase + t];
        const float z = B[2 * NPTS + jbase + t];
        sB[t] = make_float4(x, y, z, fmaf(x, x, fmaf(y, y, z * z)));
    }
    __syncthreads();

    const int i = blockIdx.x * BLOCK + threadIdx.x;
    const float px = A[i];
    const float py = A[NPTS + i];
    const float pz = A[2 * NPTS + i];
    const float m2x = -2.0f * px, m2y = -2.0f * py, m2z = -2.0f * pz;
    const float pp = fmaf(px, px, fmaf(py, py, pz * pz));

    float m = INFINITY;
#pragma unroll 8
    for (int j = 0; j < CHUNK; ++j) {
        const float4 g = sB[j];
        float h = fmaf(m2x, g.x, g.w);
        h = fmaf(m2y, g.y, h);
        h = fmaf(m2z, g.z, h);
        m = fminf(m, h);
    }
    partial[(blockIdx.z * NCHUNK + blockIdx.y) * NPTS + i] = m + pp;
}

// ---------------------------------------------------------------------------
// Kernel 2: finalize. One block, 1024 threads.
// For each point: d2 = min over NCHUNK partials, d = sqrt(max(d2,0)).
// Reduce sums + threshold counts; emit [cd, f0, f1].
// ---------------------------------------------------------------------------
__device__ inline float wave_reduce_sum(float v) {
    for (int off = 32; off > 0; off >>= 1) v += __shfl_down(v, off, 64);
    return v;
}

__global__ void __launch_bounds__(1024)
finalize_kernel(const float* __restrict__ partial,
                const float* __restrict__ threshes,
                float* __restrict__ out) {
    const float t0 = threshes[0];
    const float t1 = threshes[1];

    float sf = 0.f, sb = 0.f;
    float cf0 = 0.f, cf1 = 0.f, cb0 = 0.f, cb1 = 0.f;

    const int tid = threadIdx.x;
    for (int i = tid; i < NPTS; i += 1024) {
        float mf = INFINITY, mb = INFINITY;
#pragma unroll
        for (int c = 0; c < NCHUNK; ++c) {
            mf = fminf(mf, partial[c * NPTS + i]);
            mb = fminf(mb, partial[(NCHUNK + c) * NPTS + i]);
        }
        const float df = sqrtf(fmaxf(mf, 0.f));
        const float db = sqrtf(fmaxf(mb, 0.f));
        sf += df;
        sb += db;
        cf0 += (df <= t0) ? 1.f : 0.f;
        cf1 += (df <= t1) ? 1.f : 0.f;
        cb0 += (db <= t0) ? 1.f : 0.f;
        cb1 += (db <= t1) ? 1.f : 0.f;
    }

    sf  = wave_reduce_sum(sf);
    sb  = wave_reduce_sum(sb);
    cf0 = wave_reduce_sum(cf0);
    cf1 = wave_reduce_sum(cf1);
    cb0 = wave_reduce_sum(cb0);
    cb1 = wave_reduce_sum(cb1);

    __shared__ float red[6][16];
    const int wave = tid >> 6;
    const int lane = tid & 63;
    if (lane == 0) {
        red[0][wave] = sf;  red[1][wave] = sb;
        red[2][wave] = cf0; red[3][wave] = cf1;
        red[4][wave] = cb0; red[5][wave] = cb1;
    }
    __syncthreads();

    if (tid == 0) {
        float tsf = 0, tsb = 0, tcf0 = 0, tcf1 = 0, tcb0 = 0, tcb1 = 0;
        for (int w = 0; w < 16; ++w) {
            tsf  += red[0][w]; tsb  += red[1][w];
            tcf0 += red[2][w]; tcf1 += red[3][w];
            tcb0 += red[4][w]; tcb1 += red[5][w];
        }
        const float invn = 1.0f / (float)NPTS;
        const float cd = 0.5f * (tsf + tsb) * invn;

        const float scale = 100.0f * invn;
        const float p0 = scale * tcf0, r0 = scale * tcb0;
        const float p1 = scale * tcf1, r1 = scale * tcb1;
        const float f0 = 2.0f * p0 * r0 / (p0 + r0 + 1e-8f);
        const float f1 = 2.0f * p1 * r1 / (p1 + r1 + 1e-8f);

        out[0] = cd;
        out[1] = f0;
        out[2] = f1;
    }
}

// ---------------------------------------------------------------------------
extern "C" void kernel_launch(void* const* d_in, const int* in_sizes, int n_in,
                              void* d_out, int out_size, void* d_ws, size_t ws_size,
                              hipStream_t stream) {
    const float* predict  = (const float*)d_in[0];  // [1,3,8192] planar
    const float* gt       = (const float*)d_in[1];  // [1,3,8192] planar
    const float* threshes = (const float*)d_in[2];  // [2]
    float* out = (float*)d_out;

    float* partial = (float*)d_ws;  // [2][NCHUNK][NPTS] = 512 KB

    dim3 grid(NPTS / BLOCK, NCHUNK, 2);
    nn_partial_kernel<<<grid, BLOCK, 0, stream>>>(predict, gt, partial);

    finalize_kernel<<<1, 1024, 0, stream>>>(partial, threshes, out);
}

// Round 3
// 97.194 us; speedup vs baseline: 1.4187x; 1.4187x over previous
//
#include <hip/hip_runtime.h>
#include <math.h>

#define NPTS  8192
#define BLOCK 256
#define Q     8                       // queries per thread
#define GX    (NPTS / (BLOCK * Q))    // 4 query tiles

// ---------------------------------------------------------------------------
// Kernel 1: partial NN min with Q-way register blocking.
// grid = (GX, gy, 2). z=0: queries=predict, db=gt; z=1: reversed.
// Each block stages S = NPTS/gy db points into LDS as float4 (x,y,z,|g|^2),
// then each thread scans them against its Q register-resident queries:
//   h = |g|^2 - 2 p.g  (3 FMA + 1 MIN per pair, 32 VALU per ds_read_b128)
// Writes partial[(z*gy + cy)*NPTS + i] = min_h + |p|^2. No atomics, no init.
// ---------------------------------------------------------------------------
__global__ void __launch_bounds__(BLOCK)
nn_partial(const float* __restrict__ P, const float* __restrict__ G,
           float* __restrict__ partial, int S, int gy) {
    const float* __restrict__ A = blockIdx.z ? G : P;  // queries
    const float* __restrict__ B = blockIdx.z ? P : G;  // database

    __shared__ float4 sB[1024];  // 16 KB, covers gy down to 8 (S up to 1024)

    const int jb = blockIdx.y * S;
    for (int t = threadIdx.x; t < S; t += BLOCK) {
        const float x = B[jb + t];
        const float y = B[NPTS + jb + t];
        const float z = B[2 * NPTS + jb + t];
        sB[t] = make_float4(x, y, z, fmaf(x, x, fmaf(y, y, z * z)));
    }
    __syncthreads();

    const int qbase = blockIdx.x * (BLOCK * Q) + threadIdx.x;
    float m2x[Q], m2y[Q], m2z[Q], pp[Q], m[Q];
#pragma unroll
    for (int q = 0; q < Q; ++q) {
        const int i = qbase + q * BLOCK;
        const float px = A[i];
        const float py = A[NPTS + i];
        const float pz = A[2 * NPTS + i];
        m2x[q] = -2.0f * px;
        m2y[q] = -2.0f * py;
        m2z[q] = -2.0f * pz;
        pp[q] = fmaf(px, px, fmaf(py, py, pz * pz));
        m[q] = INFINITY;
    }

#pragma unroll 2
    for (int j = 0; j < S; ++j) {
        const float4 g = sB[j];
#pragma unroll
        for (int q = 0; q < Q; ++q) {
            float h = fmaf(m2x[q], g.x, g.w);
            h = fmaf(m2y[q], g.y, h);
            h = fmaf(m2z[q], g.z, h);
            m[q] = fminf(m[q], h);
        }
    }

    float* __restrict__ outp = partial + (size_t)(blockIdx.z * gy + blockIdx.y) * NPTS;
#pragma unroll
    for (int q = 0; q < Q; ++q) outp[qbase + q * BLOCK] = m[q] + pp[q];
}

// ---------------------------------------------------------------------------
__device__ inline float wave_reduce_sum(float v) {
    for (int off = 32; off > 0; off >>= 1) v += __shfl_down(v, off, 64);
    return v;
}

// ---------------------------------------------------------------------------
// Kernel 2: per-point min over gy chunks, sqrt, per-block (sum, c0, c1).
// grid = (16, 2), block = 256; 512 points per block.
// ---------------------------------------------------------------------------
__global__ void __launch_bounds__(256)
reduce1(const float* __restrict__ partial, const float* __restrict__ threshes,
        float* __restrict__ blockred, int gy) {
    const int z = blockIdx.y;
    const float t0 = threshes[0];
    const float t1 = threshes[1];
    const float* __restrict__ base = partial + (size_t)z * gy * NPTS;

    float s = 0.f, c0 = 0.f, c1 = 0.f;
#pragma unroll
    for (int k = 0; k < 2; ++k) {
        const int i = blockIdx.x * 512 + k * 256 + threadIdx.x;
        float mn = INFINITY;
#pragma unroll 8
        for (int c = 0; c < gy; ++c) mn = fminf(mn, base[(size_t)c * NPTS + i]);
        const float d = sqrtf(fmaxf(mn, 0.f));
        s += d;
        c0 += (d <= t0) ? 1.f : 0.f;
        c1 += (d <= t1) ? 1.f : 0.f;
    }

    s  = wave_reduce_sum(s);
    c0 = wave_reduce_sum(c0);
    c1 = wave_reduce_sum(c1);

    __shared__ float red[3][4];
    const int wave = threadIdx.x >> 6;
    const int lane = threadIdx.x & 63;
    if (lane == 0) { red[0][wave] = s; red[1][wave] = c0; red[2][wave] = c1; }
    __syncthreads();

    if (threadIdx.x == 0) {
        float ts = 0.f, tc0 = 0.f, tc1 = 0.f;
        for (int w = 0; w < 4; ++w) { ts += red[0][w]; tc0 += red[1][w]; tc1 += red[2][w]; }
        float* o = blockred + (size_t)(z * 16 + blockIdx.x) * 3;
        o[0] = ts; o[1] = tc0; o[2] = tc1;
    }
}

// ---------------------------------------------------------------------------
// Kernel 3: combine 32 block triples -> [cd, f0, f1]. One wave.
// Lanes 0..15 hold fwd blocks, 16..31 hold bwd blocks.
// ---------------------------------------------------------------------------
__global__ void final_kernel(const float* __restrict__ blockred,
                             float* __restrict__ out) {
    const int t = threadIdx.x;
    float s = 0.f, c0 = 0.f, c1 = 0.f;
    if (t < 32) {
        s  = blockred[t * 3 + 0];
        c0 = blockred[t * 3 + 1];
        c1 = blockred[t * 3 + 2];
    }
    for (int off = 8; off > 0; off >>= 1) {
        s  += __shfl_down(s,  off, 16);
        c0 += __shfl_down(c0, off, 16);
        c1 += __shfl_down(c1, off, 16);
    }
    const float sb  = __shfl(s,  16, 64);
    const float cb0 = __shfl(c0, 16, 64);
    const float cb1 = __shfl(c1, 16, 64);

    if (t == 0) {
        const float invn = 1.0f / (float)NPTS;
        const float cd = 0.5f * (s + sb) * invn;
        const float scale = 100.0f * invn;
        const float p0 = scale * c0, r0 = scale * cb0;
        const float p1 = scale * c1, r1 = scale * cb1;
        out[0] = cd;
        out[1] = 2.0f * p0 * r0 / (p0 + r0 + 1e-8f);
        out[2] = 2.0f * p1 * r1 / (p1 + r1 + 1e-8f);
    }
}

// ---------------------------------------------------------------------------
extern "C" void kernel_launch(void* const* d_in, const int* in_sizes, int n_in,
                              void* d_out, int out_size, void* d_ws, size_t ws_size,
                              hipStream_t stream) {
    const float* predict  = (const float*)d_in[0];  // [1,3,8192] planar
    const float* gt       = (const float*)d_in[1];  // [1,3,8192] planar
    const float* threshes = (const float*)d_in[2];  // [2]
    float* out = (float*)d_out;

    // Pick gy (db slices) to fit workspace: partial = 2*gy*NPTS floats.
    int gy = 64;
    while (gy > 8 && (size_t)(2 * gy * NPTS + 32 * 3) * sizeof(float) > ws_size)
        gy >>= 1;
    const int S = NPTS / gy;

    float* partial  = (float*)d_ws;                       // [2][gy][NPTS]
    float* blockred = partial + (size_t)2 * gy * NPTS;    // [32][3]

    dim3 grid1(GX, gy, 2);
    nn_partial<<<grid1, BLOCK, 0, stream>>>(predict, gt, partial, S, gy);

    dim3 grid2(16, 2);
    reduce1<<<grid2, 256, 0, stream>>>(partial, threshes, blockred, gy);

    final_kernel<<<1, 64, 0, stream>>>(blockred, out);
}

// Round 4
// 85.124 us; speedup vs baseline: 1.6199x; 1.1418x over previous
//
#include <hip/hip_runtime.h>
#include <math.h>

#define NPTS  8192
#define BLOCK 256
#define Q     8                      // queries per thread
#define GX    (NPTS / (BLOCK * Q))   // 4 query tiles
#define GY    64                     // db chunks
#define S     (NPTS / GY)            // 128 db points per chunk

// ---------------------------------------------------------------------------
// Kernel 1: partial NN min. grid = (GX, GY, 2), block = 256.
// z=0: queries=predict, db=gt; z=1: reversed.
// Stages S db points into LDS as float4 (x,y,z,|g|^2); each thread scans them
// against Q register-resident queries: h = |g|^2 - 2 p.g (3 FMA + min).
// Writes partial[(z*GY + cy)*NPTS + i] = min_h + |p|^2.
// Block (0,0,0) also zeroes the 6 accumulators + ticket counter for kernel 2.
// ---------------------------------------------------------------------------
__global__ void __launch_bounds__(BLOCK)
nn_partial(const float* __restrict__ P, const float* __restrict__ G,
           float* __restrict__ partial, float* __restrict__ acc,
           unsigned int* __restrict__ ticket) {
    if (blockIdx.x == 0 && blockIdx.y == 0 && blockIdx.z == 0 && threadIdx.x < 8) {
        if (threadIdx.x < 6) acc[threadIdx.x] = 0.0f;
        if (threadIdx.x == 7) *ticket = 0u;
    }

    const float* __restrict__ A = blockIdx.z ? G : P;  // queries
    const float* __restrict__ B = blockIdx.z ? P : G;  // database

    __shared__ float4 sB[S];
    const int jb = blockIdx.y * S;
    if (threadIdx.x < S) {
        const int t = threadIdx.x;
        const float x = B[jb + t];
        const float y = B[NPTS + jb + t];
        const float z = B[2 * NPTS + jb + t];
        sB[t] = make_float4(x, y, z, fmaf(x, x, fmaf(y, y, z * z)));
    }
    __syncthreads();

    const int qbase = blockIdx.x * (BLOCK * Q) + threadIdx.x;
    float m2x[Q], m2y[Q], m2z[Q], pp[Q], m[Q];
#pragma unroll
    for (int q = 0; q < Q; ++q) {
        const int i = qbase + q * BLOCK;
        const float px = A[i];
        const float py = A[NPTS + i];
        const float pz = A[2 * NPTS + i];
        m2x[q] = -2.0f * px;
        m2y[q] = -2.0f * py;
        m2z[q] = -2.0f * pz;
        pp[q] = fmaf(px, px, fmaf(py, py, pz * pz));
        m[q] = INFINITY;
    }

    for (int j = 0; j < S; j += 4) {
        const float4 g0 = sB[j + 0];
        const float4 g1 = sB[j + 1];
        const float4 g2 = sB[j + 2];
        const float4 g3 = sB[j + 3];
#pragma unroll
        for (int q = 0; q < Q; ++q) {
            float h0 = fmaf(m2x[q], g0.x, g0.w);
            h0 = fmaf(m2y[q], g0.y, h0);
            h0 = fmaf(m2z[q], g0.z, h0);
            float h1 = fmaf(m2x[q], g1.x, g1.w);
            h1 = fmaf(m2y[q], g1.y, h1);
            h1 = fmaf(m2z[q], g1.z, h1);
            float h2 = fmaf(m2x[q], g2.x, g2.w);
            h2 = fmaf(m2y[q], g2.y, h2);
            h2 = fmaf(m2z[q], g2.z, h2);
            float h3 = fmaf(m2x[q], g3.x, g3.w);
            h3 = fmaf(m2y[q], g3.y, h3);
            h3 = fmaf(m2z[q], g3.z, h3);
            // pairwise so clang can emit v_min3_f32
            const float hA = fminf(h0, h1);
            const float hB = fminf(h2, h3);
            m[q] = fminf(m[q], fminf(hA, hB));
        }
    }

    float* __restrict__ outp = partial + (size_t)(blockIdx.z * GY + blockIdx.y) * NPTS;
#pragma unroll
    for (int q = 0; q < Q; ++q) outp[qbase + q * BLOCK] = m[q] + pp[q];
}

// ---------------------------------------------------------------------------
__device__ inline float wave_reduce_sum(float v) {
    for (int off = 32; off > 0; off >>= 1) v += __shfl_down(v, off, 64);
    return v;
}

// ---------------------------------------------------------------------------
// Kernel 2: fused reduce + finalize. grid = (32, 2), block = 256.
// Each thread owns one point: min over GY chunks, sqrt, sum + thresh counts.
// Block-reduce, atomicAdd into acc[z*3 + {0,1,2}]; last block (ticket==63)
// computes [cd, f0, f1] and writes d_out.
// ---------------------------------------------------------------------------
__global__ void __launch_bounds__(256)
reduce_final(const float* __restrict__ partial, const float* __restrict__ threshes,
             float* __restrict__ acc, unsigned int* __restrict__ ticket,
             float* __restrict__ out) {
    const int z = blockIdx.y;
    const float t0 = threshes[0];
    const float t1 = threshes[1];
    const float* __restrict__ base = partial + (size_t)z * GY * NPTS;

    const int i = blockIdx.x * 256 + threadIdx.x;
    float mn = INFINITY;
#pragma unroll 8
    for (int c = 0; c < GY; ++c) mn = fminf(mn, base[(size_t)c * NPTS + i]);
    const float d = sqrtf(fmaxf(mn, 0.f));
    float s  = d;
    float c0 = (d <= t0) ? 1.f : 0.f;
    float c1 = (d <= t1) ? 1.f : 0.f;

    s  = wave_reduce_sum(s);
    c0 = wave_reduce_sum(c0);
    c1 = wave_reduce_sum(c1);

    __shared__ float red[3][4];
    const int wave = threadIdx.x >> 6;
    const int lane = threadIdx.x & 63;
    if (lane == 0) { red[0][wave] = s; red[1][wave] = c0; red[2][wave] = c1; }
    __syncthreads();

    __shared__ unsigned int my_ticket;
    if (threadIdx.x == 0) {
        float ts = 0.f, tc0 = 0.f, tc1 = 0.f;
        for (int w = 0; w < 4; ++w) { ts += red[0][w]; tc0 += red[1][w]; tc1 += red[2][w]; }
        atomicAdd(&acc[z * 3 + 0], ts);
        atomicAdd(&acc[z * 3 + 1], tc0);
        atomicAdd(&acc[z * 3 + 2], tc1);
        __threadfence();
        my_ticket = atomicAdd(ticket, 1u);
    }
    __syncthreads();

    if (my_ticket == 63u && threadIdx.x == 0) {
        // atomic read-back (bypasses non-coherent L1)
        float a[6];
        for (int k = 0; k < 6; ++k) a[k] = atomicAdd(&acc[k], 0.0f);
        const float invn = 1.0f / (float)NPTS;
        const float cd = 0.5f * (a[0] + a[3]) * invn;
        const float scale = 100.0f * invn;
        const float p0 = scale * a[1], r0 = scale * a[4];
        const float p1 = scale * a[2], r1 = scale * a[5];
        out[0] = cd;
        out[1] = 2.0f * p0 * r0 / (p0 + r0 + 1e-8f);
        out[2] = 2.0f * p1 * r1 / (p1 + r1 + 1e-8f);
    }
}

// ---------------------------------------------------------------------------
extern "C" void kernel_launch(void* const* d_in, const int* in_sizes, int n_in,
                              void* d_out, int out_size, void* d_ws, size_t ws_size,
                              hipStream_t stream) {
    const float* predict  = (const float*)d_in[0];  // [1,3,8192] planar
    const float* gt       = (const float*)d_in[1];  // [1,3,8192] planar
    const float* threshes = (const float*)d_in[2];  // [2]
    float* out = (float*)d_out;

    float* partial = (float*)d_ws;                            // [2][GY][NPTS] = 4 MB
    float* acc     = partial + (size_t)2 * GY * NPTS;         // [6]
    unsigned int* ticket = (unsigned int*)(acc + 6);          // [1]

    dim3 grid1(GX, GY, 2);
    nn_partial<<<grid1, BLOCK, 0, stream>>>(predict, gt, partial, acc, ticket);

    dim3 grid2(32, 2);
    reduce_final<<<grid2, 256, 0, stream>>>(partial, threshes, acc, ticket, out);
}